// Round 3
// baseline (514.473 us; speedup 1.0000x reference)
//
#include <hip/hip_runtime.h>

// ---------------------------------------------------------------------------
// Problem constants: B=4, N=1024 (32x32 grid), DIM=512, HEADS=8, DH=64.
// Outputs: [4,1024,512] fp32 then softmax(dots0) [4,8,1024,1024] fp32.
// ---------------------------------------------------------------------------

__device__ __forceinline__ float wsum(float v) {
#pragma unroll
  for (int off = 32; off > 0; off >>= 1) v += __shfl_xor(v, off, 64);
  return v;
}
__device__ __forceinline__ float wmaxr(float v) {
#pragma unroll
  for (int off = 32; off > 0; off >>= 1) v = fmaxf(v, __shfl_xor(v, off, 64));
  return v;
}
__device__ __forceinline__ float wminr(float v) {
#pragma unroll
  for (int off = 32; off > 0; off >>= 1) v = fminf(v, __shfl_xor(v, off, 64));
  return v;
}

// ---------------------------------------------------------------------------
// K1: C[M,N] = A[M,K] @ B[K,N]; 128x128 tile, 8x8 microtile (split 4+4).
// M=4096, N=1536, K=512 -> all tiles exact, no bounds checks.
// ---------------------------------------------------------------------------
__global__ __launch_bounds__(256) void gemm_f32_128(
    const float* __restrict__ A, const float* __restrict__ Bm,
    float* __restrict__ C, int M, int N, int K) {
  __shared__ float As[16][132];
  __shared__ float Bs[16][132];
  const int t = threadIdx.x;
  const int bm = blockIdx.y * 128;
  const int bn = blockIdx.x * 128;
  const int tx = t & 15;
  const int ty = t >> 4;

  float acc[8][8];
#pragma unroll
  for (int i = 0; i < 8; ++i)
#pragma unroll
    for (int j = 0; j < 8; ++j) acc[i][j] = 0.0f;

  const int mr = t >> 1;
  const int kc = (t & 1) * 8;
  const int kr = t >> 4;
  const int nc = (t & 15) * 8;

  for (int k0 = 0; k0 < K; k0 += 16) {
    const float4* asrc = (const float4*)&A[(size_t)(bm + mr) * K + k0 + kc];
    const float4 a0 = asrc[0], a1 = asrc[1];
    const float4* bsrc = (const float4*)&Bm[(size_t)(k0 + kr) * N + bn + nc];
    const float4 b0 = bsrc[0], b1 = bsrc[1];
    __syncthreads();
    As[kc + 0][mr] = a0.x; As[kc + 1][mr] = a0.y;
    As[kc + 2][mr] = a0.z; As[kc + 3][mr] = a0.w;
    As[kc + 4][mr] = a1.x; As[kc + 5][mr] = a1.y;
    As[kc + 6][mr] = a1.z; As[kc + 7][mr] = a1.w;
    *(float4*)&Bs[kr][nc] = b0;
    *(float4*)&Bs[kr][nc + 4] = b1;
    __syncthreads();
#pragma unroll
    for (int kk = 0; kk < 16; ++kk) {
      const float4 aLo = *(const float4*)&As[kk][ty * 4];
      const float4 aHi = *(const float4*)&As[kk][64 + ty * 4];
      const float4 bLo = *(const float4*)&Bs[kk][tx * 4];
      const float4 bHi = *(const float4*)&Bs[kk][64 + tx * 4];
      const float av[8] = {aLo.x, aLo.y, aLo.z, aLo.w, aHi.x, aHi.y, aHi.z, aHi.w};
      const float bv[8] = {bLo.x, bLo.y, bLo.z, bLo.w, bHi.x, bHi.y, bHi.z, bHi.w};
#pragma unroll
      for (int i = 0; i < 8; ++i)
#pragma unroll
        for (int j = 0; j < 8; ++j) acc[i][j] += av[i] * bv[j];
    }
  }

#pragma unroll
  for (int i = 0; i < 8; ++i) {
    const int row = bm + ((i < 4) ? (ty * 4 + i) : (64 + ty * 4 + (i - 4)));
    float4 lo, hi;
    lo.x = acc[i][0]; lo.y = acc[i][1]; lo.z = acc[i][2]; lo.w = acc[i][3];
    hi.x = acc[i][4]; hi.y = acc[i][5]; hi.z = acc[i][6]; hi.w = acc[i][7];
    *(float4*)&C[(size_t)row * N + bn + tx * 4] = lo;
    *(float4*)&C[(size_t)row * N + bn + 64 + tx * 4] = hi;
  }
}

// ---------------------------------------------------------------------------
// K3: fused attention. Grid: (32 itiles, 32 b*h). Block: 256 (4 waves).
// Each wave owns 8 query rows; full 1024-wide score row in registers s[8][16]
// (lane l owns columns j = 64*tt + l). K/V staged per 128-col tile in LDS with
// XOR swizzle d^(j&31) -> conflict-free reads, no padding (LDS stays < 64KB).
// rpi/dis computed analytically; rpb table reduced to a 2016-entry LDS slice
// (all 32 rows of a workgroup share yi = itile).
// ---------------------------------------------------------------------------
__global__ __launch_bounds__(256, 2) void attn_fused(
    const float* __restrict__ qkv,       // [4,1024,1536]
    const float* __restrict__ prob,      // [4,1024]
    const float* __restrict__ rpb,       // [3969,8]
    const float* __restrict__ headsita,  // [8]
    const float* __restrict__ w_thresh,  // [64]
    float* __restrict__ out2,            // [4,8,1024,1024] softmax(dots0)
    float* __restrict__ attnout)         // [4,1024,512]
{
  __shared__ float kv_lds[128 * 64];   // 32 KB : K tile, then V tile
  __shared__ float q_t[64 * 32];       //  8 KB : q transposed [d][row]
  __shared__ float multi[4096];        // 16 KB : rpb slice, then p chunks

  const int t = threadIdx.x;
  const int w = t >> 6;   // wave 0..3
  const int l = t & 63;   // lane
  const int itile = blockIdx.x;   // 0..31
  const int bh = blockIdx.y;      // 0..31
  const int b = bh >> 3;
  const int h = bh & 7;
  const int i0 = itile * 32;
  const int yi = itile;           // all 32 rows share yi = i>>5

  // stage rpb slice: global idx = (yi - yj + 31)*63 + (xi - xj + 31)
  //                = yi*63 + e with e = (31-yj)*63 + (xi-xj+31) in [0,2016)
#pragma unroll
  for (int c = 0; c < 8; ++c) {
    const int e = c * 256 + t;
    if (e < 2016) multi[e] = rpb[(size_t)(yi * 63 + e) * 8 + h];
  }
  // stage q transposed: q_t[d*32 + row]
#pragma unroll
  for (int c = 0; c < 8; ++c) {
    const int idx = c * 256 + t;
    const int row = idx >> 6, d = idx & 63;
    q_t[d * 32 + row] = qkv[(size_t)(b * 1024 + i0 + row) * 1536 + h * 64 + d];
  }
  __syncthreads();

  const float sita = headsita[h];
  const float factor = 1.0f / (2.0f * sita * sita + 1e-6f);
  const float wt = w_thresh[l];

  float tval[8], probv[8];
#pragma unroll
  for (int r = 0; r < 8; ++r) {
    const int row = w * 8 + r;
    float v = q_t[l * 32 + row] * wt;
    v = wsum(v);
    // sigmoid(q.w_thresh) * sigmoid(-2.0)
    tval[r] = (1.0f / (1.0f + __expf(-v))) * 0.11920292202211755f;
    probv[r] = prob[b * 1024 + i0 + row];
  }

  float s[8][16];
#pragma unroll
  for (int r = 0; r < 8; ++r)
#pragma unroll
    for (int tt = 0; tt < 16; ++tt) s[r][tt] = 0.0f;

  // ---- QK^T ----
  const size_t kbase = (size_t)b * 1024 * 1536 + 512 + h * 64;
  const int swl = l & 31;
#pragma unroll
  for (int jt = 0; jt < 8; ++jt) {
    __syncthreads();
#pragma unroll
    for (int c = 0; c < 8; ++c) {
      const int f = (c * 256 + t) * 4;
      const int j = f >> 6, d = f & 63;
      const float4 v4 = *(const float4*)&qkv[kbase + (size_t)(jt * 128 + j) * 1536 + d];
      const int sw = j & 31;
      kv_lds[j * 64 + ((d + 0) ^ sw)] = v4.x;
      kv_lds[j * 64 + ((d + 1) ^ sw)] = v4.y;
      kv_lds[j * 64 + ((d + 2) ^ sw)] = v4.z;
      kv_lds[j * 64 + ((d + 3) ^ sw)] = v4.w;
    }
    __syncthreads();
#pragma unroll 8
    for (int d = 0; d < 64; ++d) {
      const float kv0 = kv_lds[l * 64 + (d ^ swl)];
      const float kv1 = kv_lds[(64 + l) * 64 + (d ^ swl)];
      const float4 qA = *(const float4*)&q_t[d * 32 + w * 8];
      const float4 qB = *(const float4*)&q_t[d * 32 + w * 8 + 4];
      const float qa[8] = {qA.x, qA.y, qA.z, qA.w, qB.x, qB.y, qB.z, qB.w};
#pragma unroll
      for (int r = 0; r < 8; ++r) {
        s[r][jt * 2 + 0] += qa[r] * kv0;
        s[r][jt * 2 + 1] += qa[r] * kv1;
      }
    }
  }

  // ---- scale + softmax(dots0) -> out2 (nontemporal: 134MB streaming) ----
  const size_t o2base = ((size_t)(b * 8 + h)) * 1024 * 1024;
#pragma unroll
  for (int r = 0; r < 8; ++r) {
#pragma unroll
    for (int tt = 0; tt < 16; ++tt) s[r][tt] *= 0.125f;  // dh^-0.5
    float m = -1e30f;
#pragma unroll
    for (int tt = 0; tt < 16; ++tt) m = fmaxf(m, s[r][tt]);
    m = wmaxr(m);
    float e[16];
    float sum = 0.0f;
#pragma unroll
    for (int tt = 0; tt < 16; ++tt) { e[tt] = __expf(s[r][tt] - m); sum += e[tt]; }
    sum = wsum(sum);
    const float inv = 1.0f / sum;
    float* orow = out2 + o2base + (size_t)(i0 + w * 8 + r) * 1024;
#pragma unroll
    for (int tt = 0; tt < 16; ++tt)
      __builtin_nontemporal_store(e[tt] * inv, &orow[tt * 64 + l]);
  }

  // ---- add RPE bias: rpb lookup + 0.01*exp(-factor*dis), analytic idx ----
#pragma unroll
  for (int r = 0; r < 8; ++r) {
    const int xi = (w * 8 + r) & 31;  // i0 is a multiple of 32
#pragma unroll
    for (int tt = 0; tt < 16; ++tt) {
      const int j = tt * 64 + l;
      const int yj = j >> 5, xj = j & 31;
      const float rpbv = multi[(31 - yj) * 63 + (xi - xj + 31)];
      const float dy = (float)(yi - yj) * 0.03125f;
      const float dx = (float)(xi - xj) * 0.03125f;
      s[r][tt] += rpbv + 0.01f * __expf(-factor * (dy * dy + dx * dx));
    }
  }

  // ---- softmax(dots) + threshold prune + renorm ----
#pragma unroll
  for (int r = 0; r < 8; ++r) {
    float m = -1e30f, mn = 1e30f;
#pragma unroll
    for (int tt = 0; tt < 16; ++tt) { m = fmaxf(m, s[r][tt]); mn = fminf(mn, s[r][tt]); }
    m = wmaxr(m); mn = wminr(mn);
    float sum = 0.0f;
#pragma unroll
    for (int tt = 0; tt < 16; ++tt) { const float e = __expf(s[r][tt] - m); s[r][tt] = e; sum += e; }
    sum = wsum(sum);
    const float invd = 1.0f / sum;
    const float amax = invd;                 // exp(0)/sum
    const float amin = __expf(mn - m) * invd;
    const float th = amin + tval[r] * (amax - amin);
    const float ok = (probv[r] < 0.9f) ? 1.0f : 0.0f;
    float deno = 0.0f;
#pragma unroll
    for (int tt = 0; tt < 16; ++tt) {
      float a = s[r][tt] * invd * ok;     // attn * row-mask
      a = (a > th) ? a : 0.0f;            // record = attn - thresh > 0
      s[r][tt] = a;
      deno += a;
    }
    deno = wsum(deno);
    const float invden = 1.0f / (deno + 1e-6f);
#pragma unroll
    for (int tt = 0; tt < 16; ++tt) s[r][tt] *= invden;   // attn_p
  }

  // ---- PV: out[row][dd] = sum_j p[row][j] * V[j][dd]; lane = dd ----
  float outv[8];
#pragma unroll
  for (int r = 0; r < 8; ++r) outv[r] = 0.0f;
  const size_t vbase = (size_t)b * 1024 * 1536 + 1024 + h * 64;
#pragma unroll
  for (int jt = 0; jt < 8; ++jt) {
    __syncthreads();
    // each wave deposits its p chunk: multi[(w*128 + jlocal)*8 + r]
#pragma unroll
    for (int u = 0; u < 2; ++u)
#pragma unroll
      for (int r = 0; r < 8; ++r)
        multi[(w * 128 + u * 64 + l) * 8 + r] = s[r][jt * 2 + u];
    // stage V tile
#pragma unroll
    for (int c = 0; c < 8; ++c) {
      const int f = (c * 256 + t) * 4;
      const int j = f >> 6, d = f & 63;
      const float4 v4 = *(const float4*)&qkv[vbase + (size_t)(jt * 128 + j) * 1536 + d];
      const int sw = j & 31;
      kv_lds[j * 64 + ((d + 0) ^ sw)] = v4.x;
      kv_lds[j * 64 + ((d + 1) ^ sw)] = v4.y;
      kv_lds[j * 64 + ((d + 2) ^ sw)] = v4.z;
      kv_lds[j * 64 + ((d + 3) ^ sw)] = v4.w;
    }
    __syncthreads();
#pragma unroll 4
    for (int j = 0; j < 128; ++j) {
      const float vv = kv_lds[j * 64 + (l ^ (j & 31))];
      const float4 pA = *(const float4*)&multi[(w * 128 + j) * 8];
      const float4 pB = *(const float4*)&multi[(w * 128 + j) * 8 + 4];
      outv[0] += pA.x * vv; outv[1] += pA.y * vv;
      outv[2] += pA.z * vv; outv[3] += pA.w * vv;
      outv[4] += pB.x * vv; outv[5] += pB.y * vv;
      outv[6] += pB.z * vv; outv[7] += pB.w * vv;
    }
  }
#pragma unroll
  for (int r = 0; r < 8; ++r)
    attnout[(size_t)(b * 1024 + i0 + w * 8 + r) * 512 + h * 64 + l] = outv[r];
}

// ---------------------------------------------------------------------------
// K4: C[M,N] = A[M,K] @ B[K,N] + bias[N]; 64x64 tile, 4x4 microtile.
// M=4096, N=512, K=512.
// ---------------------------------------------------------------------------
__global__ __launch_bounds__(256) void gemm_f32_64_bias(
    const float* __restrict__ A, const float* __restrict__ Bm,
    const float* __restrict__ bias, float* __restrict__ C,
    int M, int N, int K) {
  __shared__ float As[16][68];
  __shared__ float Bs[16][68];
  const int t = threadIdx.x;
  const int bm = blockIdx.y * 64;
  const int bn = blockIdx.x * 64;
  const int tx = t & 15;
  const int ty = t >> 4;

  float acc[4][4];
#pragma unroll
  for (int i = 0; i < 4; ++i)
#pragma unroll
    for (int j = 0; j < 4; ++j) acc[i][j] = 0.0f;

  const int amr = t >> 2;
  const int akc = (t & 3) * 4;
  const int bkr = t >> 4;
  const int bnc = (t & 15) * 4;

  for (int k0 = 0; k0 < K; k0 += 16) {
    const float4 a0 = *(const float4*)&A[(size_t)(bm + amr) * K + k0 + akc];
    const float4 b0 = *(const float4*)&Bm[(size_t)(k0 + bkr) * N + bn + bnc];
    __syncthreads();
    As[akc + 0][amr] = a0.x; As[akc + 1][amr] = a0.y;
    As[akc + 2][amr] = a0.z; As[akc + 3][amr] = a0.w;
    *(float4*)&Bs[bkr][bnc] = b0;
    __syncthreads();
#pragma unroll
    for (int kk = 0; kk < 16; ++kk) {
      const float4 av = *(const float4*)&As[kk][ty * 4];
      const float4 bv = *(const float4*)&Bs[kk][tx * 4];
      const float aa[4] = {av.x, av.y, av.z, av.w};
      const float bb[4] = {bv.x, bv.y, bv.z, bv.w};
#pragma unroll
      for (int i = 0; i < 4; ++i)
#pragma unroll
        for (int j = 0; j < 4; ++j) acc[i][j] += aa[i] * bb[j];
    }
  }

  const float4 bi = *(const float4*)&bias[bn + tx * 4];
#pragma unroll
  for (int i = 0; i < 4; ++i) {
    float4 o;
    o.x = acc[i][0] + bi.x; o.y = acc[i][1] + bi.y;
    o.z = acc[i][2] + bi.z; o.w = acc[i][3] + bi.w;
    *(float4*)&C[(size_t)(bm + ty * 4 + i) * N + bn + tx * 4] = o;
  }
}

// ---------------------------------------------------------------------------
extern "C" void kernel_launch(void* const* d_in, const int* in_sizes, int n_in,
                              void* d_out, int out_size, void* d_ws, size_t ws_size,
                              hipStream_t stream) {
  const float* x        = (const float*)d_in[0];  // [4,1024,512]
  const float* prob     = (const float*)d_in[1];  // [4,1024]
  const float* w_qkv    = (const float*)d_in[2];  // [512,1536]
  const float* rpb      = (const float*)d_in[3];  // [3969,8]
  const float* headsita = (const float*)d_in[4];  // [8]
  const float* w_thresh = (const float*)d_in[5];  // [64]
  const float* w_out    = (const float*)d_in[6];  // [512,512]
  const float* b_out    = (const float*)d_in[7];  // [512]
  // d_in[8] = rpi, d_in[9] = dis : recomputed analytically in-kernel.

  float* out  = (float*)d_out;                       // [4,1024,512]
  float* out2 = out + (size_t)4 * 1024 * 512;        // [4,8,1024,1024]

  float* qkv     = (float*)d_ws;                     // 4*1024*1536 floats
  float* attnout = qkv + (size_t)4 * 1024 * 1536;    // 4*1024*512 floats

  // 1) QKV projection: [4096,512] @ [512,1536]
  gemm_f32_128<<<dim3(1536 / 128, 4096 / 128), 256, 0, stream>>>(
      x, w_qkv, qkv, 4096, 1536, 512);

  // 2) fused attention (writes softmax(dots0) and pre-projection output)
  attn_fused<<<dim3(32, 32), 256, 0, stream>>>(
      qkv, prob, rpb, headsita, w_thresh, out2, attnout);

  // 3) output projection + bias: [4096,512] @ [512,512]
  gemm_f32_64_bias<<<dim3(512 / 64, 4096 / 64), 256, 0, stream>>>(
      attnout, w_out, b_out, out, 4096, 512, 512);
}